// Round 1
// baseline (598.499 us; speedup 1.0000x reference)
//
#include <hip/hip_runtime.h>
#include <hip/hip_bf16.h>

#define IN_F   4096
#define OUT_F  4096
#define HID    64
#define D_LAT  16
#define BLK    16
#define NB     (IN_F * OUT_F / BLK)   // 1,048,576
#define M_TOT  8192                    // 4 * 2048
#define K_TOT  IN_F
#define N_TOT  OUT_F

typedef __bf16 bf16x8 __attribute__((ext_vector_type(8)));
typedef float  f32x4  __attribute__((ext_vector_type(4)));

// ---------------------------------------------------------------- convert x
__global__ __launch_bounds__(256) void convert_x_kernel(
    const float* __restrict__ x, __hip_bfloat16* __restrict__ xb) {
  size_t i = ((size_t)blockIdx.x * 256 + threadIdx.x) * 8;
  const float4* p = (const float4*)(x + i);
  float4 a = p[0], b = p[1];
  union { __hip_bfloat16 h[8]; uint4 q; } u;
  u.h[0] = __float2bfloat16(a.x); u.h[1] = __float2bfloat16(a.y);
  u.h[2] = __float2bfloat16(a.z); u.h[3] = __float2bfloat16(a.w);
  u.h[4] = __float2bfloat16(b.x); u.h[5] = __float2bfloat16(b.y);
  u.h[6] = __float2bfloat16(b.z); u.h[7] = __float2bfloat16(b.w);
  *(uint4*)(xb + i) = u.q;
}

// ---------------------------------------------------------------- decode W
// One thread per 16-weight block. MLP weights are wave-uniform -> scalar
// loads; h[64] lives in VGPRs (full unroll mandatory for reg indexing).
__global__ __launch_bounds__(256) void decode_kernel(
    const int* __restrict__ yidx, const float* __restrict__ codebook,
    const float* __restrict__ W1, const float* __restrict__ b1,
    const float* __restrict__ W2, const float* __restrict__ b2,
    const float* __restrict__ scale, const float* __restrict__ shift,
    __hip_bfloat16* __restrict__ What) {
  int t = threadIdx.x;
  int b = blockIdx.x * 256 + t;
  int o = blockIdx.x;  // == b >> 8 since 256 blocks-of-16 per output row
  int id = yidx[b];
  const float4* cb = (const float4*)(codebook + (size_t)id * D_LAT);
  float4 c0 = cb[0], c1 = cb[1], c2 = cb[2], c3 = cb[3];
  float code[16] = {c0.x, c0.y, c0.z, c0.w, c1.x, c1.y, c1.z, c1.w,
                    c2.x, c2.y, c2.z, c2.w, c3.x, c3.y, c3.z, c3.w};
  float h[HID];
#pragma unroll
  for (int j = 0; j < HID; j++) h[j] = b1[j];
#pragma unroll
  for (int d = 0; d < D_LAT; d++) {
    float cd = code[d];
#pragma unroll
    for (int j = 0; j < HID; j++) h[j] = fmaf(cd, W1[d * HID + j], h[j]);
  }
  float acc[BLK];
#pragma unroll
  for (int c = 0; c < BLK; c++) acc[c] = b2[c];
#pragma unroll
  for (int j = 0; j < HID; j++) {
    float hj = fmaxf(h[j], 0.f);
#pragma unroll
    for (int c = 0; c < BLK; c++) acc[c] = fmaf(hj, W2[j * BLK + c], acc[c]);
  }
  float sc = scale[o], sh = shift[o];
  union { __hip_bfloat16 h16[16]; uint4 q[2]; } u;
#pragma unroll
  for (int c = 0; c < BLK; c++) u.h16[c] = __float2bfloat16(fmaf(acc[c], sc, sh));
  uint4* dst = (uint4*)(What + (size_t)b * BLK);
  dst[0] = u.q[0];
  dst[1] = u.q[1];
}

// ---------------------------------------------------------------- GEMM
// C[m][n] = sum_k A[m][k] * B[n][k] + bias[n]   (B stored row-major [N][K])
__device__ inline void gload_lds16(const void* g, void* l) {
  __builtin_amdgcn_global_load_lds(
      (const __attribute__((address_space(1))) void*)g,
      (__attribute__((address_space(3))) void*)l, 16, 0, 0);
}

__global__ __launch_bounds__(256) void gemm_bt_kernel(
    const __hip_bfloat16* __restrict__ A, const __hip_bfloat16* __restrict__ B,
    const float* __restrict__ bias, float* __restrict__ C) {
  __shared__ __align__(16) __hip_bfloat16 sA[128 * 32];
  __shared__ __align__(16) __hip_bfloat16 sB[128 * 32];
  const int lane  = threadIdx.x & 63;
  const int wave  = threadIdx.x >> 6;
  const int m0    = blockIdx.y * 128;
  const int n0    = blockIdx.x * 128;
  const int waveM = (wave >> 1) * 64;
  const int waveN = (wave & 1) * 64;
  const int ar = lane >> 2;        // row within 16-row chunk
  const int ac = (lane & 3) * 8;   // col element (8 bf16 = 16 B)

  f32x4 acc[4][4];
#pragma unroll
  for (int i = 0; i < 4; i++)
#pragma unroll
    for (int j = 0; j < 4; j++) acc[i][j] = (f32x4){0.f, 0.f, 0.f, 0.f};

  for (int k0 = 0; k0 < K_TOT; k0 += 32) {
    // stage 128x32 bf16 tiles: 8 chunks of 1 KB each; 2 A + 2 B per wave
#pragma unroll
    for (int i = 0; i < 2; i++) {
      int ch  = wave * 2 + i;
      int row = ch * 16 + ar;
      gload_lds16(A + (size_t)(m0 + row) * K_TOT + k0 + ac, &sA[ch * 512]);
      gload_lds16(B + (size_t)(n0 + row) * K_TOT + k0 + ac, &sB[ch * 512]);
    }
    __syncthreads();
    bf16x8 af[4], bf[4];
#pragma unroll
    for (int t = 0; t < 4; t++) {
      af[t] = *(const bf16x8*)&sA[(waveM + t * 16 + (lane & 15)) * 32 + (lane >> 4) * 8];
      bf[t] = *(const bf16x8*)&sB[(waveN + t * 16 + (lane & 15)) * 32 + (lane >> 4) * 8];
    }
#pragma unroll
    for (int mt = 0; mt < 4; mt++)
#pragma unroll
      for (int nt = 0; nt < 4; nt++)
        acc[mt][nt] = __builtin_amdgcn_mfma_f32_16x16x32_bf16(
            af[mt], bf[nt], acc[mt][nt], 0, 0, 0);
    __syncthreads();
  }

  // epilogue: C/D layout col = lane&15, row = (lane>>4)*4 + r
  float bs[4];
#pragma unroll
  for (int nt = 0; nt < 4; nt++) bs[nt] = bias[n0 + waveN + nt * 16 + (lane & 15)];
#pragma unroll
  for (int mt = 0; mt < 4; mt++) {
    int r0 = m0 + waveM + mt * 16 + (lane >> 4) * 4;
#pragma unroll
    for (int nt = 0; nt < 4; nt++) {
      int cn = n0 + waveN + nt * 16 + (lane & 15);
#pragma unroll
      for (int r = 0; r < 4; r++)
        C[(size_t)(r0 + r) * N_TOT + cn] = acc[mt][nt][r] + bs[nt];
    }
  }
}

// ---------------------------------------------------------------- launch
extern "C" void kernel_launch(void* const* d_in, const int* in_sizes, int n_in,
                              void* d_out, int out_size, void* d_ws, size_t ws_size,
                              hipStream_t stream) {
  const float* x        = (const float*)d_in[0];
  const int*   yidx     = (const int*)d_in[1];
  const float* codebook = (const float*)d_in[2];
  const float* W1       = (const float*)d_in[3];
  const float* b1       = (const float*)d_in[4];
  const float* W2       = (const float*)d_in[5];
  const float* b2       = (const float*)d_in[6];
  const float* scale    = (const float*)d_in[7];
  const float* shift    = (const float*)d_in[8];
  const float* bias     = (const float*)d_in[9];
  float* out = (float*)d_out;

  __hip_bfloat16* What = (__hip_bfloat16*)d_ws;                                  // 32 MB
  __hip_bfloat16* xb   = (__hip_bfloat16*)((char*)d_ws + (size_t)32 * 1024 * 1024); // 64 MB

  convert_x_kernel<<<(M_TOT * (size_t)K_TOT) / (256 * 8), 256, 0, stream>>>(x, xb);
  decode_kernel<<<NB / 256, 256, 0, stream>>>(yidx, codebook, W1, b1, W2, b2,
                                              scale, shift, What);
  gemm_bt_kernel<<<dim3(N_TOT / 128, M_TOT / 128), 256, 0, stream>>>(xb, What, bias, out);
}

// Round 2
// 562.894 us; speedup vs baseline: 1.0633x; 1.0633x over previous
//
#include <hip/hip_runtime.h>
#include <hip/hip_bf16.h>

#define IN_F   4096
#define OUT_F  4096
#define HID    64
#define D_LAT  16
#define BLK    16
#define NB     (IN_F * OUT_F / BLK)   // 1,048,576
#define M_TOT  8192                    // 4 * 2048
#define K_TOT  IN_F
#define N_TOT  OUT_F

typedef __bf16 bf16x8 __attribute__((ext_vector_type(8)));
typedef float  f32x4  __attribute__((ext_vector_type(4)));

// ---------------------------------------------------------------- convert x
__global__ __launch_bounds__(256) void convert_x_kernel(
    const float* __restrict__ x, __hip_bfloat16* __restrict__ xb) {
  size_t i = ((size_t)blockIdx.x * 256 + threadIdx.x) * 8;
  const float4* p = (const float4*)(x + i);
  float4 a = p[0], b = p[1];
  union { __hip_bfloat16 h[8]; uint4 q; } u;
  u.h[0] = __float2bfloat16(a.x); u.h[1] = __float2bfloat16(a.y);
  u.h[2] = __float2bfloat16(a.z); u.h[3] = __float2bfloat16(a.w);
  u.h[4] = __float2bfloat16(b.x); u.h[5] = __float2bfloat16(b.y);
  u.h[6] = __float2bfloat16(b.z); u.h[7] = __float2bfloat16(b.w);
  *(uint4*)(xb + i) = u.q;
}

// ---------------------------------------------------------------- decode W
__global__ __launch_bounds__(256) void decode_kernel(
    const int* __restrict__ yidx, const float* __restrict__ codebook,
    const float* __restrict__ W1, const float* __restrict__ b1,
    const float* __restrict__ W2, const float* __restrict__ b2,
    const float* __restrict__ scale, const float* __restrict__ shift,
    __hip_bfloat16* __restrict__ What) {
  int t = threadIdx.x;
  int b = blockIdx.x * 256 + t;
  int o = blockIdx.x;  // == b >> 8 since 256 blocks-of-16 per output row
  int id = yidx[b];
  const float4* cb = (const float4*)(codebook + (size_t)id * D_LAT);
  float4 c0 = cb[0], c1 = cb[1], c2 = cb[2], c3 = cb[3];
  float code[16] = {c0.x, c0.y, c0.z, c0.w, c1.x, c1.y, c1.z, c1.w,
                    c2.x, c2.y, c2.z, c2.w, c3.x, c3.y, c3.z, c3.w};
  float h[HID];
#pragma unroll
  for (int j = 0; j < HID; j++) h[j] = b1[j];
#pragma unroll
  for (int d = 0; d < D_LAT; d++) {
    float cd = code[d];
#pragma unroll
    for (int j = 0; j < HID; j++) h[j] = fmaf(cd, W1[d * HID + j], h[j]);
  }
  float acc[BLK];
#pragma unroll
  for (int c = 0; c < BLK; c++) acc[c] = b2[c];
#pragma unroll
  for (int j = 0; j < HID; j++) {
    float hj = fmaxf(h[j], 0.f);
#pragma unroll
    for (int c = 0; c < BLK; c++) acc[c] = fmaf(hj, W2[j * BLK + c], acc[c]);
  }
  float sc = scale[o], sh = shift[o];
  union { __hip_bfloat16 h16[16]; uint4 q[2]; } u;
#pragma unroll
  for (int c = 0; c < BLK; c++) u.h16[c] = __float2bfloat16(fmaf(acc[c], sc, sh));
  uint4* dst = (uint4*)(What + (size_t)b * BLK);
  dst[0] = u.q[0];
  dst[1] = u.q[1];
}

// ---------------------------------------------------------------- GEMM
// C[m][n] = sum_k A[m][k] * B[n][k] + bias[n]   (B row-major [N][K])
// Block tile 256x128, BK=32. 4 waves in 2x2; wave tile 128x64 = 8x4 MFMAs.
// LDS layout: per row (64 B = 4 chunks of 16 B), chunk c stored at position
// c ^ ((row>>1)&3). Swizzle applied on the staging side by permuting each
// lane's GLOBAL source chunk (global_load_lds dest is fixed base+lane*16).
// Read side: each 32-lane phase of ds_read_b128 touches all 32 banks
// uniformly 4x -> zero non-structural conflicts.
__device__ inline void gload_lds16(const void* g, void* l) {
  __builtin_amdgcn_global_load_lds(
      (const __attribute__((address_space(1))) void*)g,
      (__attribute__((address_space(3))) void*)l, 16, 0, 0);
}

__global__ __launch_bounds__(256, 2) void gemm_bt_kernel(
    const __hip_bfloat16* __restrict__ A, const __hip_bfloat16* __restrict__ B,
    const float* __restrict__ bias, float* __restrict__ C) {
  __shared__ __align__(16) __hip_bfloat16 sA[256 * 32];  // 16 KB
  __shared__ __align__(16) __hip_bfloat16 sB[128 * 32];  //  8 KB
  const int lane = threadIdx.x & 63;
  const int wave = threadIdx.x >> 6;
  const int m0 = blockIdx.y * 256;
  const int n0 = blockIdx.x * 128;
  const int wr = wave >> 1;          // 0..1 -> rows wr*128
  const int wc = wave & 1;           // 0..1 -> cols wc*64

  // ---- staging source pointers (swizzled chunk is lane-only, loop-invariant)
  const int srow = lane >> 2;                        // 0..15 within 16-row chunk
  const int schk = (lane & 3) ^ ((lane >> 3) & 3);   // swizzled source chunk
  // A: wave handles chunks wave*4+i (i=0..3) -> rows wave*64 + i*16 + srow
  const __hip_bfloat16* aSrc =
      A + (size_t)(m0 + wave * 64 + srow) * K_TOT + schk * 8;
  // B: wave handles chunks wave*2+i (i=0..1) -> rows wave*32 + i*16 + srow
  const __hip_bfloat16* bSrc =
      B + (size_t)(n0 + wave * 32 + srow) * K_TOT + schk * 8;

  // ---- fragment read addresses (lane-only swizzle pos)
  const int fl = lane & 15;
  const int pos = (lane >> 4) ^ ((fl >> 1) & 3);     // swizzled chunk position
  const __hip_bfloat16* aRd = &sA[(wr * 128 + fl) * 32 + pos * 8];
  const __hip_bfloat16* bRd = &sB[(wc * 64 + fl) * 32 + pos * 8];

  f32x4 acc[8][4];
#pragma unroll
  for (int i = 0; i < 8; i++)
#pragma unroll
    for (int j = 0; j < 4; j++) acc[i][j] = (f32x4){0.f, 0.f, 0.f, 0.f};

  for (int k0 = 0; k0 < K_TOT; k0 += 32) {
#pragma unroll
    for (int i = 0; i < 4; i++)   // 4 A-chunks of 16 rows (1 KB each)
      gload_lds16(aSrc + (size_t)i * 16 * K_TOT + k0,
                  (char*)sA + (wave * 4 + i) * 1024);
#pragma unroll
    for (int i = 0; i < 2; i++)   // 2 B-chunks
      gload_lds16(bSrc + (size_t)i * 16 * K_TOT + k0,
                  (char*)sB + (wave * 2 + i) * 1024);
    __syncthreads();

    bf16x8 bf[4];
#pragma unroll
    for (int nt = 0; nt < 4; nt++) bf[nt] = *(const bf16x8*)(bRd + nt * 16 * 32);
#pragma unroll
    for (int mt = 0; mt < 8; mt++) {
      bf16x8 af = *(const bf16x8*)(aRd + mt * 16 * 32);
#pragma unroll
      for (int nt = 0; nt < 4; nt++)
        acc[mt][nt] = __builtin_amdgcn_mfma_f32_16x16x32_bf16(
            af, bf[nt], acc[mt][nt], 0, 0, 0);
    }
    __syncthreads();
  }

  // epilogue: C/D layout col = lane&15, row = (lane>>4)*4 + r
  float bs[4];
#pragma unroll
  for (int nt = 0; nt < 4; nt++) bs[nt] = bias[n0 + wc * 64 + nt * 16 + fl];
#pragma unroll
  for (int mt = 0; mt < 8; mt++) {
    int r0 = m0 + wr * 128 + mt * 16 + (lane >> 4) * 4;
#pragma unroll
    for (int nt = 0; nt < 4; nt++) {
      int cn = n0 + wc * 64 + nt * 16 + fl;
#pragma unroll
      for (int r = 0; r < 4; r++)
        C[(size_t)(r0 + r) * N_TOT + cn] = acc[mt][nt][r] + bs[nt];
    }
  }
}

// ---------------------------------------------------------------- launch
extern "C" void kernel_launch(void* const* d_in, const int* in_sizes, int n_in,
                              void* d_out, int out_size, void* d_ws, size_t ws_size,
                              hipStream_t stream) {
  const float* x        = (const float*)d_in[0];
  const int*   yidx     = (const int*)d_in[1];
  const float* codebook = (const float*)d_in[2];
  const float* W1       = (const float*)d_in[3];
  const float* b1       = (const float*)d_in[4];
  const float* W2       = (const float*)d_in[5];
  const float* b2       = (const float*)d_in[6];
  const float* scale    = (const float*)d_in[7];
  const float* shift    = (const float*)d_in[8];
  const float* bias     = (const float*)d_in[9];
  float* out = (float*)d_out;

  __hip_bfloat16* What = (__hip_bfloat16*)d_ws;                                  // 32 MB
  __hip_bfloat16* xb   = (__hip_bfloat16*)((char*)d_ws + (size_t)32 * 1024 * 1024); // 64 MB

  convert_x_kernel<<<(M_TOT * (size_t)K_TOT) / (256 * 8), 256, 0, stream>>>(x, xb);
  decode_kernel<<<NB / 256, 256, 0, stream>>>(yidx, codebook, W1, b1, W2, b2,
                                              scale, shift, What);
  gemm_bt_kernel<<<dim3(N_TOT / 128, M_TOT / 256), 256, 0, stream>>>(xb, What, bias, out);
}

// Round 3
// 546.454 us; speedup vs baseline: 1.0952x; 1.0301x over previous
//
#include <hip/hip_runtime.h>
#include <hip/hip_bf16.h>

#define IN_F   4096
#define OUT_F  4096
#define HID    64
#define D_LAT  16
#define BLK    16
#define NB     (IN_F * OUT_F / BLK)   // 1,048,576
#define M_TOT  8192                    // 4 * 2048
#define K_TOT  IN_F
#define N_TOT  OUT_F

typedef __bf16 bf16x8 __attribute__((ext_vector_type(8)));
typedef float  f32x4  __attribute__((ext_vector_type(4)));

// ---------------------------------------------------------------- convert x
__global__ __launch_bounds__(256) void convert_x_kernel(
    const float* __restrict__ x, __hip_bfloat16* __restrict__ xb) {
  size_t i = ((size_t)blockIdx.x * 256 + threadIdx.x) * 8;
  const float4* p = (const float4*)(x + i);
  float4 a = p[0], b = p[1];
  union { __hip_bfloat16 h[8]; uint4 q; } u;
  u.h[0] = __float2bfloat16(a.x); u.h[1] = __float2bfloat16(a.y);
  u.h[2] = __float2bfloat16(a.z); u.h[3] = __float2bfloat16(a.w);
  u.h[4] = __float2bfloat16(b.x); u.h[5] = __float2bfloat16(b.y);
  u.h[6] = __float2bfloat16(b.z); u.h[7] = __float2bfloat16(b.w);
  *(uint4*)(xb + i) = u.q;
}

// ---------------------------------------------------------------- decode W (MFMA)
// codes[NB,16] @ W1[16,64] -> relu -> @ W2[64,16], then scale/shift.
// Per wave-step: 16 codes. Layer1 = 4x mfma_16x16x32 (K padded 16->32 with
// zeros: quads 2,3 supply zero A and zero B). h exits in C/D layout
// (row=(q)*4+r, col=lane&15); round-trip through LDS (row stride 72 bf16 for
// bank spread) to re-enter as A-operand layout (m=lane&15, k=q*8+j).
__global__ __launch_bounds__(256) void decode_mfma_kernel(
    const int* __restrict__ yidx, const float* __restrict__ codebook,
    const float* __restrict__ W1, const float* __restrict__ b1,
    const float* __restrict__ W2, const float* __restrict__ b2,
    const float* __restrict__ scale, const float* __restrict__ shift,
    __hip_bfloat16* __restrict__ What) {
  __shared__ __align__(16) __hip_bfloat16 sH[4][16 * 72];  // per-wave h tile
  const int lane = threadIdx.x & 63;
  const int wave = threadIdx.x >> 6;
  const int n = lane & 15;   // col within 16
  const int q = lane >> 4;   // quad
  const bool act = q < 2;    // quads holding real K (k<16) for layer 1

  // zero bf16 vector
  union { __hip_bfloat16 h[8]; bf16x8 v; } uz;
#pragma unroll
  for (int j = 0; j < 8; j++) uz.h[j] = __float2bfloat16(0.f);
  const bf16x8 zf = uz.v;
  const f32x4 z4 = (f32x4){0.f, 0.f, 0.f, 0.f};

  // B-frags layer1: frag1[g][j] = W1[k][g*16+n], k=q*8+j (zero for k>=16)
  bf16x8 frag1[4];
#pragma unroll
  for (int g = 0; g < 4; g++) {
    union { __hip_bfloat16 h[8]; bf16x8 v; } u;
#pragma unroll
    for (int j = 0; j < 8; j++) {
      int k = (q * 8 + j) & 15;  // keep in-bounds even when masked
      float w = act ? W1[k * HID + g * 16 + n] : 0.f;
      u.h[j] = __float2bfloat16(w);
    }
    frag1[g] = u.v;
  }
  // B-frags layer2: frag2[kk][j] = W2[(kk*32+q*8+j)*16 + n]
  bf16x8 frag2[2];
#pragma unroll
  for (int kk = 0; kk < 2; kk++) {
    union { __hip_bfloat16 h[8]; bf16x8 v; } u;
#pragma unroll
    for (int j = 0; j < 8; j++)
      u.h[j] = __float2bfloat16(W2[(kk * 32 + q * 8 + j) * BLK + n]);
    frag2[kk] = u.v;
  }
  float b1v[4];
#pragma unroll
  for (int g = 0; g < 4; g++) b1v[g] = b1[g * 16 + n];
  const float b2v = b2[n];

  const int c0w = blockIdx.x * 256 + wave * 64;
#pragma unroll 1
  for (int i = 0; i < 4; i++) {
    const int cbase = c0w + i * 16;
    // gather codes -> A frag (m=n holds code row, k=q*8+j; quads 2,3 zero)
    const int id = yidx[cbase + n];
    const float4* cp = (const float4*)(codebook + (size_t)id * D_LAT + (q & 1) * 8);
    float4 ca = cp[0], cb = cp[1];
    union { __hip_bfloat16 h[8]; bf16x8 v; } ua;
    ua.h[0] = __float2bfloat16(ca.x); ua.h[1] = __float2bfloat16(ca.y);
    ua.h[2] = __float2bfloat16(ca.z); ua.h[3] = __float2bfloat16(ca.w);
    ua.h[4] = __float2bfloat16(cb.x); ua.h[5] = __float2bfloat16(cb.y);
    ua.h[6] = __float2bfloat16(cb.z); ua.h[7] = __float2bfloat16(cb.w);
    bf16x8 afrag = act ? ua.v : zf;

    f32x4 hC[4];
#pragma unroll
    for (int g = 0; g < 4; g++)
      hC[g] = __builtin_amdgcn_mfma_f32_16x16x32_bf16(afrag, frag1[g], z4, 0, 0, 0);

    __syncthreads();  // previous step's LDS reads complete
#pragma unroll
    for (int g = 0; g < 4; g++)
#pragma unroll
      for (int r = 0; r < 4; r++) {
        float hv = fmaxf(hC[g][r] + b1v[g], 0.f);
        sH[wave][(q * 4 + r) * 72 + g * 16 + n] = __float2bfloat16(hv);
      }
    __syncthreads();  // writes visible

    bf16x8 a2_0 = *(const bf16x8*)&sH[wave][n * 72 + q * 8];
    bf16x8 a2_1 = *(const bf16x8*)&sH[wave][n * 72 + 32 + q * 8];
    f32x4 o4 = __builtin_amdgcn_mfma_f32_16x16x32_bf16(a2_0, frag2[0], z4, 0, 0, 0);
    o4 = __builtin_amdgcn_mfma_f32_16x16x32_bf16(a2_1, frag2[1], o4, 0, 0, 0);

    const int o = cbase >> 8;  // all 16 codes share one output row
    const float sc = scale[o], sh = shift[o];
#pragma unroll
    for (int r = 0; r < 4; r++) {
      int code = cbase + q * 4 + r;
      What[(size_t)code * BLK + n] = __float2bfloat16((o4[r] + b2v) * sc + sh);
    }
  }
}

// ---------------------------------------------------------------- GEMM
// C[m][n] = sum_k A[m][k] * B[n][k] + bias[n]   (B row-major [N][K])
// Block tile 256x128, BK=32. 4 waves in 2x2; wave tile 128x64 = 8x4 MFMAs.
// XOR chunk swizzle on the staging side kills LDS bank conflicts (R2: 0).
__device__ inline void gload_lds16(const void* g, void* l) {
  __builtin_amdgcn_global_load_lds(
      (const __attribute__((address_space(1))) void*)g,
      (__attribute__((address_space(3))) void*)l, 16, 0, 0);
}

__global__ __launch_bounds__(256, 2) void gemm_bt_kernel(
    const __hip_bfloat16* __restrict__ A, const __hip_bfloat16* __restrict__ B,
    const float* __restrict__ bias, float* __restrict__ C) {
  __shared__ __align__(16) __hip_bfloat16 sA[256 * 32];  // 16 KB
  __shared__ __align__(16) __hip_bfloat16 sB[128 * 32];  //  8 KB
  const int lane = threadIdx.x & 63;
  const int wave = threadIdx.x >> 6;
  const int m0 = blockIdx.y * 256;
  const int n0 = blockIdx.x * 128;
  const int wr = wave >> 1;
  const int wc = wave & 1;

  const int srow = lane >> 2;
  const int schk = (lane & 3) ^ ((lane >> 3) & 3);
  const __hip_bfloat16* aSrc =
      A + (size_t)(m0 + wave * 64 + srow) * K_TOT + schk * 8;
  const __hip_bfloat16* bSrc =
      B + (size_t)(n0 + wave * 32 + srow) * K_TOT + schk * 8;

  const int fl = lane & 15;
  const int pos = (lane >> 4) ^ ((fl >> 1) & 3);
  const __hip_bfloat16* aRd = &sA[(wr * 128 + fl) * 32 + pos * 8];
  const __hip_bfloat16* bRd = &sB[(wc * 64 + fl) * 32 + pos * 8];

  f32x4 acc[8][4];
#pragma unroll
  for (int i = 0; i < 8; i++)
#pragma unroll
    for (int j = 0; j < 4; j++) acc[i][j] = (f32x4){0.f, 0.f, 0.f, 0.f};

  for (int k0 = 0; k0 < K_TOT; k0 += 32) {
#pragma unroll
    for (int i = 0; i < 4; i++)
      gload_lds16(aSrc + (size_t)i * 16 * K_TOT + k0,
                  (char*)sA + (wave * 4 + i) * 1024);
#pragma unroll
    for (int i = 0; i < 2; i++)
      gload_lds16(bSrc + (size_t)i * 16 * K_TOT + k0,
                  (char*)sB + (wave * 2 + i) * 1024);
    __syncthreads();

    bf16x8 bf[4];
#pragma unroll
    for (int nt = 0; nt < 4; nt++) bf[nt] = *(const bf16x8*)(bRd + nt * 16 * 32);
#pragma unroll
    for (int mt = 0; mt < 8; mt++) {
      bf16x8 af = *(const bf16x8*)(aRd + mt * 16 * 32);
#pragma unroll
      for (int nt = 0; nt < 4; nt++)
        acc[mt][nt] = __builtin_amdgcn_mfma_f32_16x16x32_bf16(
            af, bf[nt], acc[mt][nt], 0, 0, 0);
    }
    __syncthreads();
  }

  float bs[4];
#pragma unroll
  for (int nt = 0; nt < 4; nt++) bs[nt] = bias[n0 + wc * 64 + nt * 16 + fl];
#pragma unroll
  for (int mt = 0; mt < 8; mt++) {
    int r0 = m0 + wr * 128 + mt * 16 + (lane >> 4) * 4;
#pragma unroll
    for (int nt = 0; nt < 4; nt++) {
      int cn = n0 + wc * 64 + nt * 16 + fl;
#pragma unroll
      for (int r = 0; r < 4; r++)
        C[(size_t)(r0 + r) * N_TOT + cn] = acc[mt][nt][r] + bs[nt];
    }
  }
}

// ---------------------------------------------------------------- launch
extern "C" void kernel_launch(void* const* d_in, const int* in_sizes, int n_in,
                              void* d_out, int out_size, void* d_ws, size_t ws_size,
                              hipStream_t stream) {
  const float* x        = (const float*)d_in[0];
  const int*   yidx     = (const int*)d_in[1];
  const float* codebook = (const float*)d_in[2];
  const float* W1       = (const float*)d_in[3];
  const float* b1       = (const float*)d_in[4];
  const float* W2       = (const float*)d_in[5];
  const float* b2       = (const float*)d_in[6];
  const float* scale    = (const float*)d_in[7];
  const float* shift    = (const float*)d_in[8];
  const float* bias     = (const float*)d_in[9];
  float* out = (float*)d_out;

  __hip_bfloat16* What = (__hip_bfloat16*)d_ws;                                  // 32 MB
  __hip_bfloat16* xb   = (__hip_bfloat16*)((char*)d_ws + (size_t)32 * 1024 * 1024); // 64 MB

  convert_x_kernel<<<(M_TOT * (size_t)K_TOT) / (256 * 8), 256, 0, stream>>>(x, xb);
  decode_mfma_kernel<<<NB / 256, 256, 0, stream>>>(yidx, codebook, W1, b1, W2, b2,
                                                   scale, shift, What);
  gemm_bt_kernel<<<dim3(N_TOT / 128, M_TOT / 256), 256, 0, stream>>>(xb, What, bias, out);
}